// Round 10
// baseline (302.620 us; speedup 1.0000x reference)
//
#include <hip/hip_runtime.h>
#include <math.h>

#define S_LEN 2048
#define DH 64
#define BH_N 64
#define BQ 128
#define KT 64

typedef __attribute__((ext_vector_type(8))) short bf16x8;
typedef __attribute__((ext_vector_type(4))) float f32x4;

__device__ __forceinline__ unsigned short f2bf(float f) {
  unsigned int u = __float_as_uint(f);
  u += 0x7fffu + ((u >> 16) & 1u);
  return (unsigned short)(u >> 16);
}

__device__ __forceinline__ unsigned cvt_pk(float lo, float hi) {
  unsigned r;
  asm("v_cvt_pk_bf16_f32 %0, %1, %2" : "=v"(r) : "v"(lo), "v"(hi));
  return r;
}

// R9 base (XCD swizzle + nt W/O stores + __syncthreads). Changes:
//  (1) 4-tile staging groups: barriers 32 -> 16 (amortize store-drain).
//  (2) cvt_pk staging converts + uint4/uint2 LDS writes (4x fewer VALU,
//      8x fewer ds_writes on the barrier-bounded stage phase).
__global__ __launch_bounds__(256, 2)
void curve_attn_kernel(const float* __restrict__ Qg,
                       const float* __restrict__ Kg,
                       const float* __restrict__ Vg,
                       float* __restrict__ Og,
                       float* __restrict__ Wg,
                       float sc_l2e, float neg_l2C)
{
  __shared__ unsigned short ldsK[4][64 * 64];   // [tile][k_local][d], swizzled
  __shared__ unsigned short ldsV[4][64 * 64];   // [tile][d][k_local], swizzled
  __shared__ unsigned short ldsW[4][32 * 64];   // per-wave [q_local][k_local], swizzled

  const int tid  = threadIdx.x;
  const int lane = tid & 63;
  const int wv   = tid >> 6;
  const int lr   = lane & 15;
  const int lg   = lane >> 4;

  // XCD-aware swizzle (nwg = 1024, 8 XCDs, 128 blocks per XCD chunk)
  const int bid = (blockIdx.x & 7) * 128 + (blockIdx.x >> 3);
  const int bh  = bid >> 4;
  const int qt  = (bid & 15) * BQ;

  const size_t sd = (size_t)S_LEN * DH;
  const float* Qb = Qg + (size_t)bh * sd;
  const float* Kb = Kg + (size_t)bh * sd;
  const float* Vb = Vg + (size_t)bh * sd;
  float* Ob = Og + (size_t)bh * sd;
  float* Wb = Wg + (size_t)bh * (size_t)S_LEN * S_LEN;

  const int qrow0 = qt + wv * 32;

  // ---- Q fragments (R1 verbatim): A-frag m=lr, k=8*lg+i ----
  bf16x8 qf[2][2];
#pragma unroll
  for (int mb = 0; mb < 2; ++mb)
#pragma unroll
    for (int kb = 0; kb < 2; ++kb) {
      const float* src = Qb + (size_t)(qrow0 + mb * 16 + lr) * DH + kb * 32 + lg * 8;
      float4 a = *(const float4*)src;
      float4 b = *(const float4*)(src + 4);
      bf16x8 q;
      q[0] = (short)f2bf(a.x); q[1] = (short)f2bf(a.y);
      q[2] = (short)f2bf(a.z); q[3] = (short)f2bf(a.w);
      q[4] = (short)f2bf(b.x); q[5] = (short)f2bf(b.y);
      q[6] = (short)f2bf(b.z); q[7] = (short)f2bf(b.w);
      qf[mb][kb] = q;
    }

  f32x4 oacc[2][4];
#pragma unroll
  for (int i = 0; i < 2; ++i)
#pragma unroll
    for (int j = 0; j < 4; ++j)
      oacc[i][j] = (f32x4){0.f, 0.f, 0.f, 0.f};

  // staging thread mapping (R2-style: 16 consecutive d per thread for K)
  const int krow = tid >> 2;            // K row 0..63
  const int kcol = (tid & 3) << 4;      // K col base {0,16,32,48}
  const int vkb  = (tid >> 4) << 2;     // V k-row quad base
  const int vdb  = (tid & 15) << 2;     // V d-col quad base

  auto stage = [&](int t0, int buf) {
    // K tile: load 16 consecutive d, cvt_pk, 2x uint4 LDS writes
    {
      const float* ks = Kb + (size_t)(t0 + krow) * DH + kcol;
      float4 k0 = *(const float4*)(ks + 0);
      float4 k1 = *(const float4*)(ks + 4);
      float4 k2 = *(const float4*)(ks + 8);
      float4 k3 = *(const float4*)(ks + 12);
      unsigned a0 = cvt_pk(k0.x, k0.y), a1 = cvt_pk(k0.z, k0.w);
      unsigned a2 = cvt_pk(k1.x, k1.y), a3 = cvt_pk(k1.z, k1.w);
      unsigned a4 = cvt_pk(k2.x, k2.y), a5 = cvt_pk(k2.z, k2.w);
      unsigned a6 = cvt_pk(k3.x, k3.y), a7 = cvt_pk(k3.z, k3.w);
      int kswz = (krow & 7) << 3;
      int e0 = (krow * 64 + kcol) ^ kswz;
      int e1 = (krow * 64 + kcol + 8) ^ kswz;
      uint4 w0 = {a0, a1, a2, a3}, w1 = {a4, a5, a6, a7};
      *(uint4*)&ldsK[buf][e0] = w0;
      *(uint4*)&ldsK[buf][e1] = w1;
    }
    // V tile transposed: 4 k-rows x 4 d; pack along k, uint2 writes
    {
      const float* vs = Vb + (size_t)(t0 + vkb) * DH + vdb;
      float4 v0 = *(const float4*)(vs);
      float4 v1 = *(const float4*)(vs + DH);
      float4 v2 = *(const float4*)(vs + 2 * DH);
      float4 v3 = *(const float4*)(vs + 3 * DH);
#pragma unroll
      for (int jj = 0; jj < 4; ++jj) {
        int d = vdb + jj;
        unsigned p0 = cvt_pk(((const float*)&v0)[jj], ((const float*)&v1)[jj]);
        unsigned p1 = cvt_pk(((const float*)&v2)[jj], ((const float*)&v3)[jj]);
        int e = (d * 64 + vkb) ^ ((d & 7) << 3);
        uint2 pp = {p0, p1};
        *(uint2*)&ldsV[buf][e] = pp;
      }
    }
  };

  auto compute = [&](int buf, int kt) {
    // ---- QK^T (R1 verbatim): A=Q, B=K -> C[m=q][n=k] ----
    f32x4 sacc[2][4];
#pragma unroll
    for (int i = 0; i < 2; ++i)
#pragma unroll
      for (int j = 0; j < 4; ++j)
        sacc[i][j] = (f32x4){0.f, 0.f, 0.f, 0.f};

#pragma unroll
    for (int db = 0; db < 2; ++db) {
      bf16x8 kf[4];
#pragma unroll
      for (int nb = 0; nb < 4; ++nb) {
        int row = nb * 16 + lr;
        int e   = (row * 64 + db * 32 + lg * 8) ^ ((row & 7) << 3);
        kf[nb] = *(const bf16x8*)&ldsK[buf][e];
      }
#pragma unroll
      for (int mb = 0; mb < 2; ++mb)
#pragma unroll
        for (int nb = 0; nb < 4; ++nb)
          sacc[mb][nb] = __builtin_amdgcn_mfma_f32_16x16x32_bf16(
              qf[mb][db], kf[nb], sacc[mb][nb], 0, 0, 0);
    }

    // ---- epilogue: exp + nt scalar W stores + ldsW (R9 verbatim) ----
#pragma unroll
    for (int mb = 0; mb < 2; ++mb)
#pragma unroll
      for (int nb = 0; nb < 4; ++nb) {
        float wvv[4];
#pragma unroll
        for (int r = 0; r < 4; ++r)
          wvv[r] = exp2f(sacc[mb][nb][r] * sc_l2e + neg_l2C);
        float* dst = Wb + (size_t)(qrow0 + mb * 16 + lg * 4) * S_LEN + kt + nb * 16 + lr;
#pragma unroll
        for (int r = 0; r < 4; ++r)
          __builtin_nontemporal_store(wvv[r], dst + (size_t)r * S_LEN);
#pragma unroll
        for (int r = 0; r < 4; ++r) {
          int row = mb * 16 + lg * 4 + r;
          int e   = (row * 64 + nb * 16 + lr) ^ ((row & 7) << 3);
          ldsW[wv][e] = f2bf(wvv[r]);
        }
      }

    // ---- PV (R1 verbatim): A=W, B=V -> C[m=q][n=d] ----
#pragma unroll
    for (int kb = 0; kb < 2; ++kb) {
      bf16x8 af[2];
#pragma unroll
      for (int mb = 0; mb < 2; ++mb) {
        int row = mb * 16 + lr;
        int e   = (row * 64 + kb * 32 + lg * 8) ^ ((row & 7) << 3);
        af[mb] = *(const bf16x8*)&ldsW[wv][e];
      }
#pragma unroll
      for (int db = 0; db < 4; ++db) {
        int row = db * 16 + lr;
        int e   = (row * 64 + kb * 32 + lg * 8) ^ ((row & 7) << 3);
        bf16x8 vf = *(const bf16x8*)&ldsV[buf][e];
#pragma unroll
        for (int mb = 0; mb < 2; ++mb)
          oacc[mb][db] = __builtin_amdgcn_mfma_f32_16x16x32_bf16(
              af[mb], vf, oacc[mb][db], 0, 0, 0);
      }
    }
  };

  // ---- main loop: 4 tiles per sync pair (16 barriers total) ----
#pragma unroll 1
  for (int kt = 0; kt < S_LEN; kt += 4 * KT) {
    __syncthreads();            // protect LDS from previous group's readers
    stage(kt, 0);
    stage(kt + KT, 1);
    stage(kt + 2 * KT, 2);
    stage(kt + 3 * KT, 3);
    __syncthreads();
    compute(0, kt);
    compute(1, kt + KT);
    compute(2, kt + 2 * KT);
    compute(3, kt + 3 * KT);
  }

  // ---- write O (nt, R9 verbatim) ----
#pragma unroll
  for (int mb = 0; mb < 2; ++mb)
#pragma unroll
    for (int db = 0; db < 4; ++db) {
      float* dst = Ob + (size_t)(qrow0 + mb * 16 + lg * 4) * DH + db * 16 + lr;
#pragma unroll
      for (int r = 0; r < 4; ++r)
        __builtin_nontemporal_store(oacc[mb][db][r], dst + (size_t)r * DH);
    }
}

extern "C" void kernel_launch(void* const* d_in, const int* in_sizes, int n_in,
                              void* d_out, int out_size, void* d_ws, size_t ws_size,
                              hipStream_t stream) {
  const float* Q = (const float*)d_in[0];
  const float* K = (const float*)d_in[1];
  const float* V = (const float*)d_in[2];
  float* O = (float*)d_out;
  float* W = O + (size_t)BH_N * S_LEN * DH;

  const double E = 2.718281828459045235360287;
  double C = 1.0 + exp(E);
  float neg_l2C = (float)(-(log(C) / log(2.0)));
  float sc_l2e  = (float)(0.125 / log(2.0));

  curve_attn_kernel<<<dim3(BH_N * (S_LEN / BQ)), dim3(256), 0, stream>>>(
      Q, K, V, O, W, sc_l2e, neg_l2C);
}

// Round 11
// 262.075 us; speedup vs baseline: 1.1547x; 1.1547x over previous
//
#include <hip/hip_runtime.h>
#include <math.h>

#define S_LEN 2048
#define DH 64
#define BH_N 64
#define BQ 128
#define KT 64

typedef __attribute__((ext_vector_type(8))) short bf16x8;
typedef __attribute__((ext_vector_type(4))) float f32x4;
typedef __attribute__((ext_vector_type(4))) short s16x4;

__device__ __forceinline__ unsigned short f2bf(float f) {
  unsigned int u = __float_as_uint(f);
  u += 0x7fffu + ((u >> 16) & 1u);
  return (unsigned short)(u >> 16);
}

// R9 base (XCD swizzle + 2-tile groups + nt W/O stores). Single change:
// epilogue W-store loop order. Per mb: compute all 16 wvv, then store with
// nb INNERMOST so consecutive store instructions hit the SAME 4 rows at
// ADJACENT 64B columns -> DRAM write-combining sees 256B sequential bursts
// per row instead of 64B-then-jump (the fills' efficiency pattern).
__global__ __launch_bounds__(256, 2)
void curve_attn_kernel(const float* __restrict__ Qg,
                       const float* __restrict__ Kg,
                       const float* __restrict__ Vg,
                       float* __restrict__ Og,
                       float* __restrict__ Wg,
                       float sc_l2e, float neg_l2C)
{
  __shared__ unsigned short ldsK[2][64 * 64];   // [tile][k_local][d], swizzled
  __shared__ unsigned short ldsV[2][64 * 64];   // [tile][d][k_local], swizzled
  __shared__ unsigned short ldsW[4][32 * 64];   // per-wave [q_local][k_local], swizzled

  const int tid  = threadIdx.x;
  const int lane = tid & 63;
  const int wv   = tid >> 6;
  const int lr   = lane & 15;
  const int lg   = lane >> 4;

  // XCD-aware swizzle (nwg = 1024, 8 XCDs, 128 blocks per XCD chunk)
  const int bid = (blockIdx.x & 7) * 128 + (blockIdx.x >> 3);
  const int bh  = bid >> 4;
  const int qt  = (bid & 15) * BQ;

  const size_t sd = (size_t)S_LEN * DH;
  const float* Qb = Qg + (size_t)bh * sd;
  const float* Kb = Kg + (size_t)bh * sd;
  const float* Vb = Vg + (size_t)bh * sd;
  float* Ob = Og + (size_t)bh * sd;
  float* Wb = Wg + (size_t)bh * (size_t)S_LEN * S_LEN;

  const int qrow0 = qt + wv * 32;

  // ---- Q fragments (R1 verbatim): A-frag m=lr, k=8*lg+i ----
  bf16x8 qf[2][2];
#pragma unroll
  for (int mb = 0; mb < 2; ++mb)
#pragma unroll
    for (int kb = 0; kb < 2; ++kb) {
      const float* src = Qb + (size_t)(qrow0 + mb * 16 + lr) * DH + kb * 32 + lg * 8;
      float4 a = *(const float4*)src;
      float4 b = *(const float4*)(src + 4);
      bf16x8 q;
      q[0] = (short)f2bf(a.x); q[1] = (short)f2bf(a.y);
      q[2] = (short)f2bf(a.z); q[3] = (short)f2bf(a.w);
      q[4] = (short)f2bf(b.x); q[5] = (short)f2bf(b.y);
      q[6] = (short)f2bf(b.z); q[7] = (short)f2bf(b.w);
      qf[mb][kb] = q;
    }

  f32x4 oacc[2][4];
#pragma unroll
  for (int i = 0; i < 2; ++i)
#pragma unroll
    for (int j = 0; j < 4; ++j)
      oacc[i][j] = (f32x4){0.f, 0.f, 0.f, 0.f};

  // staging thread mapping (R1 verbatim)
  const int kr = tid >> 2;          // K row 0..63
  const int kc = (tid & 3) * 4;     // K col base {0,4,8,12}
  const int vr = (tid >> 4) * 4;    // V k-row quad base
  const int vc = (tid & 15) * 4;    // V d-col quad base

  auto stage = [&](int t0, int buf) {
    // K tile
    {
      const float* src = Kb + (size_t)(t0 + kr) * DH + kc;
#pragma unroll
      for (int j = 0; j < 4; ++j) {
        float4 v = *(const float4*)(src + 16 * j);
        int e  = kr * 64 + kc + 16 * j;
        int se = e ^ ((kr & 7) << 3);
        s16x4 p;
        p[0] = (short)f2bf(v.x); p[1] = (short)f2bf(v.y);
        p[2] = (short)f2bf(v.z); p[3] = (short)f2bf(v.w);
        *(s16x4*)&ldsK[buf][se] = p;
      }
    }
    // V tile (transposed)
    {
      float4 vv[4];
      const float* src = Vb + (size_t)(t0 + vr) * DH + vc;
#pragma unroll
      for (int jr = 0; jr < 4; ++jr)
        vv[jr] = *(const float4*)(src + jr * DH);
#pragma unroll
      for (int jj = 0; jj < 4; ++jj) {
        int row = vc + jj;            // d index
        int e   = row * 64 + vr;      // col = k index
        int se  = e ^ ((row & 7) << 3);
        s16x4 p;
        p[0] = (short)f2bf(((const float*)&vv[0])[jj]);
        p[1] = (short)f2bf(((const float*)&vv[1])[jj]);
        p[2] = (short)f2bf(((const float*)&vv[2])[jj]);
        p[3] = (short)f2bf(((const float*)&vv[3])[jj]);
        *(s16x4*)&ldsV[buf][se] = p;
      }
    }
  };

  auto compute = [&](int buf, int kt) {
    // ---- QK^T (R1 verbatim): A=Q, B=K -> C[m=q][n=k] ----
    f32x4 sacc[2][4];
#pragma unroll
    for (int i = 0; i < 2; ++i)
#pragma unroll
      for (int j = 0; j < 4; ++j)
        sacc[i][j] = (f32x4){0.f, 0.f, 0.f, 0.f};

#pragma unroll
    for (int db = 0; db < 2; ++db) {
      bf16x8 kf[4];
#pragma unroll
      for (int nb = 0; nb < 4; ++nb) {
        int row = nb * 16 + lr;
        int e   = (row * 64 + db * 32 + lg * 8) ^ ((row & 7) << 3);
        kf[nb] = *(const bf16x8*)&ldsK[buf][e];
      }
#pragma unroll
      for (int mb = 0; mb < 2; ++mb)
#pragma unroll
        for (int nb = 0; nb < 4; ++nb)
          sacc[mb][nb] = __builtin_amdgcn_mfma_f32_16x16x32_bf16(
              qf[mb][db], kf[nb], sacc[mb][nb], 0, 0, 0);
    }

    // ---- epilogue: exp; nt W stores with nb-INNER order (burst-friendly);
    //      then ldsW writes (values/addresses identical to R9) ----
#pragma unroll
    for (int mb = 0; mb < 2; ++mb) {
      float wvv[4][4];                      // [nb][r]
#pragma unroll
      for (int nb = 0; nb < 4; ++nb)
#pragma unroll
        for (int r = 0; r < 4; ++r)
          wvv[nb][r] = exp2f(sacc[mb][nb][r] * sc_l2e + neg_l2C);

      float* base = Wb + (size_t)(qrow0 + mb * 16 + lg * 4) * S_LEN + kt + lr;
#pragma unroll
      for (int r = 0; r < 4; ++r)
#pragma unroll
        for (int nb = 0; nb < 4; ++nb)
          __builtin_nontemporal_store(wvv[nb][r],
                                      base + (size_t)r * S_LEN + nb * 16);

#pragma unroll
      for (int nb = 0; nb < 4; ++nb)
#pragma unroll
        for (int r = 0; r < 4; ++r) {
          int row = mb * 16 + lg * 4 + r;
          int e   = (row * 64 + nb * 16 + lr) ^ ((row & 7) << 3);
          ldsW[wv][e] = f2bf(wvv[nb][r]);
        }
    }

    // ---- PV (R1 verbatim): A=W, B=V -> C[m=q][n=d] ----
#pragma unroll
    for (int kb = 0; kb < 2; ++kb) {
      bf16x8 af[2];
#pragma unroll
      for (int mb = 0; mb < 2; ++mb) {
        int row = mb * 16 + lr;
        int e   = (row * 64 + kb * 32 + lg * 8) ^ ((row & 7) << 3);
        af[mb] = *(const bf16x8*)&ldsW[wv][e];
      }
#pragma unroll
      for (int db = 0; db < 4; ++db) {
        int row = db * 16 + lr;
        int e   = (row * 64 + kb * 32 + lg * 8) ^ ((row & 7) << 3);
        bf16x8 vf = *(const bf16x8*)&ldsV[buf][e];
#pragma unroll
        for (int mb = 0; mb < 2; ++mb)
          oacc[mb][db] = __builtin_amdgcn_mfma_f32_16x16x32_bf16(
              af[mb], vf, oacc[mb][db], 0, 0, 0);
      }
    }
  };

  // ---- main loop: 2 tiles per sync pair (R9-verbatim schedule) ----
#pragma unroll 1
  for (int kt = 0; kt < S_LEN; kt += 2 * KT) {
    __syncthreads();            // protect LDS from previous iteration's readers
    stage(kt, 0);
    stage(kt + KT, 1);
    __syncthreads();
    compute(0, kt);
    compute(1, kt + KT);
  }

  // ---- write O (nt, R9 verbatim) ----
#pragma unroll
  for (int mb = 0; mb < 2; ++mb)
#pragma unroll
    for (int db = 0; db < 4; ++db) {
      float* dst = Ob + (size_t)(qrow0 + mb * 16 + lg * 4) * DH + db * 16 + lr;
#pragma unroll
      for (int r = 0; r < 4; ++r)
        __builtin_nontemporal_store(oacc[mb][db][r], dst + (size_t)r * DH);
    }
}

extern "C" void kernel_launch(void* const* d_in, const int* in_sizes, int n_in,
                              void* d_out, int out_size, void* d_ws, size_t ws_size,
                              hipStream_t stream) {
  const float* Q = (const float*)d_in[0];
  const float* K = (const float*)d_in[1];
  const float* V = (const float*)d_in[2];
  float* O = (float*)d_out;
  float* W = O + (size_t)BH_N * S_LEN * DH;

  const double E = 2.718281828459045235360287;
  double C = 1.0 + exp(E);
  float neg_l2C = (float)(-(log(C) / log(2.0)));
  float sc_l2e  = (float)(0.125 / log(2.0));

  curve_attn_kernel<<<dim3(BH_N * (S_LEN / BQ)), dim3(256), 0, stream>>>(
      Q, K, V, O, W, sc_l2e, neg_l2C);
}